// Round 2
// baseline (12192.816 us; speedup 1.0000x reference)
//
#include <hip/hip_runtime.h>
#include <float.h>
#include <math.h>

// Transformer forward, fp32 baseline (round 1: + ws_size guard, else identical).
// B=2, N=1024, D=1024, H=16, DH=64, L=6, INNER=2730.
// Workspace layout (floats):
//   X (2M) | H (2M) | Q (2M) | KV (4M) | O (2M) | P2 (2M) | PR (16.85M)
// PR is reused: attention probs [16][1024][1028] per batch, then FF u/gg.
// Total ws requirement: 31,522,816 floats = 126,091,264 bytes.

#define N_SEQ 1024
#define DMODEL 1024
#define NH 16
#define DH 64
#define NLAYER 6
#define FF_INNER 2730
#define PSTRIDE 1028  // padded row stride for probs rows of length 1025

// ---------------- block reductions (256 threads = 4 waves) ----------------
__device__ __forceinline__ float wave_sum(float v) {
#pragma unroll
  for (int o = 32; o > 0; o >>= 1) v += __shfl_xor(v, o, 64);
  return v;
}
__device__ __forceinline__ float wave_max(float v) {
#pragma unroll
  for (int o = 32; o > 0; o >>= 1) v = fmaxf(v, __shfl_xor(v, o, 64));
  return v;
}
__device__ __forceinline__ float block_sum(float v, float* s) {
  v = wave_sum(v);
  __syncthreads();
  if ((threadIdx.x & 63) == 0) s[threadIdx.x >> 6] = v;
  __syncthreads();
  return s[0] + s[1] + s[2] + s[3];
}
__device__ __forceinline__ float block_max(float v, float* s) {
  v = wave_max(v);
  __syncthreads();
  if ((threadIdx.x & 63) == 0) s[threadIdx.x >> 6] = v;
  __syncthreads();
  return fmaxf(fmaxf(s[0], s[1]), fmaxf(s[2], s[3]));
}

// ---------------- LayerNorm (optionally residual-add into out) ----------------
// RES==0: out = LN(in)*g + b.  RES==1: out += LN(in)*g + b.
template <int RES>
__global__ __launch_bounds__(256) void ln_kernel(const float* __restrict__ in,
                                                 const float* __restrict__ gw,
                                                 const float* __restrict__ bw,
                                                 float* __restrict__ out) {
  __shared__ float red[4];
  const int row = blockIdx.x, t = threadIdx.x;
  float4 v = *(const float4*)(in + (size_t)row * DMODEL + t * 4);
  float mean = block_sum(v.x + v.y + v.z + v.w, red) * (1.0f / DMODEL);
  float4 d = make_float4(v.x - mean, v.y - mean, v.z - mean, v.w - mean);
  float var = block_sum(d.x * d.x + d.y * d.y + d.z * d.z + d.w * d.w, red) * (1.0f / DMODEL);
  float rstd = rsqrtf(var + 1e-5f);
  float4 g4 = *(const float4*)(gw + t * 4);
  float4 b4 = *(const float4*)(bw + t * 4);
  float4 r = make_float4(d.x * rstd * g4.x + b4.x, d.y * rstd * g4.y + b4.y,
                         d.z * rstd * g4.z + b4.z, d.w * rstd * g4.w + b4.w);
  float* q = out + (size_t)row * DMODEL + t * 4;
  if (RES) {
    float4 xv = *(float4*)q;
    r.x += xv.x; r.y += xv.y; r.z += xv.z; r.w += xv.w;
  }
  *(float4*)q = r;
}

// ---------------- final: x / rowmax(x), then LN ----------------
__global__ __launch_bounds__(256) void final_kernel(const float* __restrict__ in,
                                                    const float* __restrict__ gw,
                                                    const float* __restrict__ bw,
                                                    float* __restrict__ out) {
  __shared__ float red[4];
  const int row = blockIdx.x, t = threadIdx.x;
  float4 v = *(const float4*)(in + (size_t)row * DMODEL + t * 4);
  float mx = block_max(fmaxf(fmaxf(v.x, v.y), fmaxf(v.z, v.w)), red);
  float4 y = make_float4(v.x / mx, v.y / mx, v.z / mx, v.w / mx);
  float mean = block_sum(y.x + y.y + y.z + y.w, red) * (1.0f / DMODEL);
  float4 d = make_float4(y.x - mean, y.y - mean, y.z - mean, y.w - mean);
  float var = block_sum(d.x * d.x + d.y * d.y + d.z * d.z + d.w * d.w, red) * (1.0f / DMODEL);
  float rstd = rsqrtf(var + 1e-5f);
  float4 g4 = *(const float4*)(gw + t * 4);
  float4 b4 = *(const float4*)(bw + t * 4);
  float4 r = make_float4(d.x * rstd * g4.x + b4.x, d.y * rstd * g4.y + b4.y,
                         d.z * rstd * g4.z + b4.z, d.w * rstd * g4.w + b4.w);
  *(float4*)(out + (size_t)row * DMODEL + t * 4) = r;
}

// ---------------- generic fp32 GEMM: C[M,N] = A[M,K] @ W[K,N] (+bias) ----------------
// 128x128 tile, BK=16, 256 threads, 8x8 microtile.
__global__ __launch_bounds__(256) void gemm_bias(const float* __restrict__ A,
                                                 const float* __restrict__ W,
                                                 const float* __restrict__ bias,
                                                 float* __restrict__ C,
                                                 int M, int N, int K) {
  __shared__ float As[16][132];  // [k][m]
  __shared__ float Bs[16][132];  // [k][n]
  const int m0 = blockIdx.y * 128, n0 = blockIdx.x * 128;
  const int t = threadIdx.x, tx = t & 15, ty = t >> 4;
  float acc[8][8];
#pragma unroll
  for (int i = 0; i < 8; i++)
#pragma unroll
    for (int j = 0; j < 8; j++) acc[i][j] = 0.f;

  for (int k0 = 0; k0 < K; k0 += 16) {
#pragma unroll
    for (int r = 0; r < 2; r++) {  // A tile: 128 rows x 16 k
      int f = t + r * 256;
      int m = f >> 2, k4 = (f & 3) << 2;
      int gm = m0 + m, gk = k0 + k4;
      float e0 = 0, e1 = 0, e2 = 0, e3 = 0;
      if (gm < M) {
        if (gk + 3 < K) {
          float4 v = *(const float4*)(A + (size_t)gm * K + gk);
          e0 = v.x; e1 = v.y; e2 = v.z; e3 = v.w;
        } else {
          if (gk + 0 < K) e0 = A[(size_t)gm * K + gk + 0];
          if (gk + 1 < K) e1 = A[(size_t)gm * K + gk + 1];
          if (gk + 2 < K) e2 = A[(size_t)gm * K + gk + 2];
          if (gk + 3 < K) e3 = A[(size_t)gm * K + gk + 3];
        }
      }
      As[k4 + 0][m] = e0; As[k4 + 1][m] = e1; As[k4 + 2][m] = e2; As[k4 + 3][m] = e3;
    }
#pragma unroll
    for (int r = 0; r < 2; r++) {  // B tile: 16 k x 128 n
      int f = t + r * 256;
      int k = f >> 5, n4 = (f & 31) << 2;
      int gk = k0 + k, gn = n0 + n4;
      float4 v = make_float4(0, 0, 0, 0);
      if (gk < K) {
        if (gn + 3 < N) {
          v = *(const float4*)(W + (size_t)gk * N + gn);
        } else {
          if (gn + 0 < N) v.x = W[(size_t)gk * N + gn + 0];
          if (gn + 1 < N) v.y = W[(size_t)gk * N + gn + 1];
          if (gn + 2 < N) v.z = W[(size_t)gk * N + gn + 2];
          if (gn + 3 < N) v.w = W[(size_t)gk * N + gn + 3];
        }
      }
      *(float4*)&Bs[k][n4] = v;
    }
    __syncthreads();
#pragma unroll
    for (int k = 0; k < 16; k++) {
      float a[8], b[8];
      *(float4*)&a[0] = *(const float4*)&As[k][ty * 8];
      *(float4*)&a[4] = *(const float4*)&As[k][ty * 8 + 4];
      *(float4*)&b[0] = *(const float4*)&Bs[k][tx * 8];
      *(float4*)&b[4] = *(const float4*)&Bs[k][tx * 8 + 4];
#pragma unroll
      for (int i = 0; i < 8; i++)
#pragma unroll
        for (int j = 0; j < 8; j++) acc[i][j] = fmaf(a[i], b[j], acc[i][j]);
    }
    __syncthreads();
  }
#pragma unroll
  for (int i = 0; i < 8; i++) {
    int gm = m0 + ty * 8 + i;
    if (gm >= M) continue;
#pragma unroll
    for (int j0 = 0; j0 < 8; j0 += 4) {
      int gn = n0 + tx * 8 + j0;
      if (gn + 3 < N) {
        float4 bv = make_float4(0, 0, 0, 0);
        if (bias) bv = *(const float4*)(bias + gn);
        float4 o = make_float4(acc[i][j0 + 0] + bv.x, acc[i][j0 + 1] + bv.y,
                               acc[i][j0 + 2] + bv.z, acc[i][j0 + 3] + bv.w);
        *(float4*)(C + (size_t)gm * N + gn) = o;
      } else {
        for (int j = 0; j < 4; j++)
          if (gn + j < N) C[(size_t)gm * N + gn + j] = acc[i][j0 + j] + (bias ? bias[gn + j] : 0.f);
      }
    }
  }
}

// ---------------- attention scores: sim[h,i,j] = SCALE * q[i]·k[j], causal mask ----------------
// grid (17 j-tiles, 16 i-tiles, 16 heads); k row j=0 is null_k, j>=1 is kv[j-1].
__global__ __launch_bounds__(256) void scores_kernel(const float* __restrict__ q,
                                                     const float* __restrict__ kv,
                                                     const float* __restrict__ nullk,
                                                     float* __restrict__ probs, int b) {
  __shared__ float Qs[64][68];  // [d][i]
  __shared__ float Ks[64][68];  // [d][j]
  const int h = blockIdx.z, i0 = blockIdx.y * 64, j0 = blockIdx.x * 64;
  const int t = threadIdx.x, tx = t & 15, ty = t >> 4;
#pragma unroll
  for (int r = 0; r < 4; r++) {
    int f = t + r * 256;
    int i = f >> 4, d4 = (f & 15) << 2;
    float4 v = *(const float4*)(q + ((size_t)(b * N_SEQ) + i0 + i) * DMODEL + h * DH + d4);
    Qs[d4 + 0][i] = v.x; Qs[d4 + 1][i] = v.y; Qs[d4 + 2][i] = v.z; Qs[d4 + 3][i] = v.w;
  }
#pragma unroll
  for (int r = 0; r < 4; r++) {
    int f = t + r * 256;
    int j = f >> 4, d4 = (f & 15) << 2;
    int jg = j0 + j;
    float4 v = make_float4(0, 0, 0, 0);
    if (jg == 0)
      v = *(const float4*)(nullk + h * DH + d4);
    else if (jg < N_SEQ + 1)
      v = *(const float4*)(kv + ((size_t)(b * N_SEQ) + jg - 1) * 2048 + h * DH + d4);
    Ks[d4 + 0][j] = v.x; Ks[d4 + 1][j] = v.y; Ks[d4 + 2][j] = v.z; Ks[d4 + 3][j] = v.w;
  }
  __syncthreads();
  float acc[4][4];
#pragma unroll
  for (int i = 0; i < 4; i++)
#pragma unroll
    for (int j = 0; j < 4; j++) acc[i][j] = 0.f;
#pragma unroll 16
  for (int d = 0; d < 64; d++) {
    float av[4], bv[4];
    *(float4*)av = *(const float4*)&Qs[d][ty * 4];
    *(float4*)bv = *(const float4*)&Ks[d][tx * 4];
#pragma unroll
    for (int i = 0; i < 4; i++)
#pragma unroll
      for (int j = 0; j < 4; j++) acc[i][j] = fmaf(av[i], bv[j], acc[i][j]);
  }
#pragma unroll
  for (int ii = 0; ii < 4; ii++) {
    int i = i0 + ty * 4 + ii;
#pragma unroll
    for (int jj = 0; jj < 4; jj++) {
      int j = j0 + tx * 4 + jj;
      if (j < N_SEQ + 1) {
        float s = acc[ii][jj] * 0.125f;  // SCALE = 64^-0.5
        if (j > i + 1) s = -FLT_MAX;     // causal (null slot j=0 never masked)
        probs[((size_t)h * N_SEQ + i) * PSTRIDE + j] = s;
      }
    }
  }
}

// ---------------- row softmax over 1025 entries ----------------
__global__ __launch_bounds__(256) void softmax_kernel(float* __restrict__ probs) {
  __shared__ float red[4];
  const int row = blockIdx.x;  // h*1024 + i
  float* p = probs + (size_t)row * PSTRIDE;
  const int t = threadIdx.x;
  float v[5];
#pragma unroll
  for (int c = 0; c < 5; c++) {
    int j = t + c * 256;
    v[c] = (j < N_SEQ + 1) ? p[j] : -FLT_MAX;
  }
  float m = fmaxf(fmaxf(fmaxf(v[0], v[1]), fmaxf(v[2], v[3])), v[4]);
  m = block_max(m, red);
  float s = 0.f;
#pragma unroll
  for (int c = 0; c < 5; c++) {
    v[c] = expf(v[c] - m);  // masked: expf(-huge) -> 0
    s += v[c];
  }
  s = block_sum(s, red);
#pragma unroll
  for (int c = 0; c < 5; c++) {
    int j = t + c * 256;
    if (j < N_SEQ + 1) p[j] = v[c] / s;
  }
}

// ---------------- talking-heads mix (in place): a'[g] = sum_h talk[g][h] * a[h] ----------------
__global__ __launch_bounds__(256) void mix_kernel(float* __restrict__ probs,
                                                  const float* __restrict__ talk) {
  __shared__ float tk[256];
  const int i = blockIdx.x;
  tk[threadIdx.x] = talk[threadIdx.x];
  __syncthreads();
  for (int j = threadIdx.x; j < N_SEQ + 1; j += 256) {
    float a[16];
#pragma unroll
    for (int hh = 0; hh < 16; hh++) a[hh] = probs[((size_t)hh * N_SEQ + i) * PSTRIDE + j];
#pragma unroll
    for (int g = 0; g < 16; g++) {
      float s = 0.f;
#pragma unroll
      for (int hh = 0; hh < 16; hh++) s = fmaf(tk[g * 16 + hh], a[hh], s);
      probs[((size_t)g * N_SEQ + i) * PSTRIDE + j] = s;
    }
  }
}

// ---------------- AV: o[b,i,h*64+d] = sum_j p[h,i,j] * v[h,j,d] ----------------
// grid (16 i-tiles, 16 heads). v row j=0 is null_v, j>=1 is kv[j-1] second half.
__global__ __launch_bounds__(256) void av_kernel(const float* __restrict__ probs,
                                                 const float* __restrict__ kv,
                                                 const float* __restrict__ nullv,
                                                 float* __restrict__ o, int b) {
  __shared__ float Ps[32][68];  // [j][i]
  __shared__ float Vs[32][68];  // [j][d]
  const int h = blockIdx.y, i0 = blockIdx.x * 64;
  const int t = threadIdx.x, tx = t & 15, ty = t >> 4;
  float acc[4][4];
#pragma unroll
  for (int i = 0; i < 4; i++)
#pragma unroll
    for (int j = 0; j < 4; j++) acc[i][j] = 0.f;

  for (int j0 = 0; j0 < N_SEQ + 1; j0 += 32) {
#pragma unroll
    for (int r = 0; r < 2; r++) {  // P: 64 i x 32 j
      int f = t + r * 256;
      int i = f >> 3, j4 = (f & 7) << 2;
      const float* src = probs + ((size_t)h * N_SEQ + i0 + i) * PSTRIDE + j0 + j4;
      float e[4];
      if (j0 + j4 + 3 < N_SEQ + 1) {
        float4 v = *(const float4*)src;
        e[0] = v.x; e[1] = v.y; e[2] = v.z; e[3] = v.w;
      } else {
#pragma unroll
        for (int c = 0; c < 4; c++) e[c] = (j0 + j4 + c < N_SEQ + 1) ? src[c] : 0.f;
      }
      Ps[j4 + 0][i] = e[0]; Ps[j4 + 1][i] = e[1]; Ps[j4 + 2][i] = e[2]; Ps[j4 + 3][i] = e[3];
    }
#pragma unroll
    for (int r = 0; r < 2; r++) {  // V: 32 j x 64 d
      int f = t + r * 256;
      int j = f >> 4, d4 = (f & 15) << 2;
      int jg = j0 + j;
      float4 v = make_float4(0, 0, 0, 0);
      if (jg == 0)
        v = *(const float4*)(nullv + h * DH + d4);
      else if (jg < N_SEQ + 1)
        v = *(const float4*)(kv + ((size_t)(b * N_SEQ) + jg - 1) * 2048 + 1024 + h * DH + d4);
      *(float4*)&Vs[j][d4] = v;
    }
    __syncthreads();
#pragma unroll 8
    for (int jj = 0; jj < 32; jj++) {
      float av[4], bv[4];
      *(float4*)av = *(const float4*)&Ps[jj][ty * 4];
      *(float4*)bv = *(const float4*)&Vs[jj][tx * 4];
#pragma unroll
      for (int i = 0; i < 4; i++)
#pragma unroll
        for (int j = 0; j < 4; j++) acc[i][j] = fmaf(av[i], bv[j], acc[i][j]);
    }
    __syncthreads();
  }
#pragma unroll
  for (int ii = 0; ii < 4; ii++) {
    float4 v = make_float4(acc[ii][0], acc[ii][1], acc[ii][2], acc[ii][3]);
    *(float4*)(o + ((size_t)(b * N_SEQ) + i0 + ty * 4 + ii) * DMODEL + h * DH + tx * 4) = v;
  }
}

// ---------------- GEGLU: gg[i,c] = u[i,c] * gelu_exact(u[i,INNER+c]) ----------------
__global__ __launch_bounds__(256) void geglu_kernel(const float* __restrict__ u,
                                                    float* __restrict__ gg) {
  const int i = blockIdx.y;
  const int j = blockIdx.x * 256 + threadIdx.x;
  if (j < FF_INNER) {
    float a = u[(size_t)i * (2 * FF_INNER) + j];
    float x = u[(size_t)i * (2 * FF_INNER) + FF_INNER + j];
    float ge = 0.5f * x * (1.0f + erff(x * 0.70710678118654752f));
    gg[(size_t)i * FF_INNER + j] = a * ge;
  }
}

// ---------------- launcher ----------------
extern "C" void kernel_launch(void* const* d_in, const int* in_sizes, int n_in,
                              void* d_out, int out_size, void* d_ws, size_t ws_size,
                              hipStream_t stream) {
  const float* xin        = (const float*)d_in[0];
  const float* attn_pre_g = (const float*)d_in[1];
  const float* attn_pre_b = (const float*)d_in[2];
  const float* attn_post_g= (const float*)d_in[3];
  const float* attn_post_b= (const float*)d_in[4];
  const float* Wq         = (const float*)d_in[5];
  const float* Wkv        = (const float*)d_in[6];
  const float* Wo         = (const float*)d_in[7];
  const float* bo         = (const float*)d_in[8];
  const float* null_k     = (const float*)d_in[9];
  const float* null_v     = (const float*)d_in[10];
  const float* talk       = (const float*)d_in[11];
  const float* ff_pre_g   = (const float*)d_in[12];
  const float* ff_pre_b   = (const float*)d_in[13];
  const float* ff_post_g  = (const float*)d_in[14];
  const float* ff_post_b  = (const float*)d_in[15];
  const float* W1         = (const float*)d_in[16];
  const float* b1         = (const float*)d_in[17];
  const float* W2         = (const float*)d_in[18];
  const float* b2         = (const float*)d_in[19];
  const float* final_g    = (const float*)d_in[20];
  const float* final_b    = (const float*)d_in[21];

  // Workspace requirement: 31,522,816 floats = 126,091,264 bytes.
  // If the harness gave us less, bail cleanly (output stays poisoned ->
  // clear "incorrect" verdict instead of an OOB write killing the container).
  const size_t WS_FLOATS_NEEDED = (size_t)31522816;
  if (ws_size < WS_FLOATS_NEEDED * sizeof(float)) return;

  float* ws = (float*)d_ws;
  float* X  = ws;                          // [2048][1024]
  float* Hh = X  + (size_t)2048 * 1024;    // [2048][1024]
  float* Q  = Hh + (size_t)2048 * 1024;    // [2048][1024]
  float* KV = Q  + (size_t)2048 * 1024;    // [2048][2048]
  float* O  = KV + (size_t)2048 * 2048;    // [2048][1024]
  float* P2 = O  + (size_t)2048 * 1024;    // [2048][1024]
  float* PR = P2 + (size_t)2048 * 1024;    // probs [16][1024][1028] / FF u,gg
  float* U  = PR;                          // [2048][5460]
  float* GG = PR + (size_t)2048 * 5460;    // [2048][2730]

  hipMemcpyAsync(X, xin, (size_t)2048 * 1024 * sizeof(float),
                 hipMemcpyDeviceToDevice, stream);

  dim3 blk(256);
  for (int l = 0; l < NLAYER; l++) {
    ln_kernel<0><<<2048, blk, 0, stream>>>(X, attn_pre_g + l * 1024, attn_pre_b + l * 1024, Hh);
    gemm_bias<<<dim3(8, 16), blk, 0, stream>>>(Hh, Wq + (size_t)l * 1024 * 1024, nullptr, Q,
                                               2048, 1024, 1024);
    gemm_bias<<<dim3(16, 16), blk, 0, stream>>>(Hh, Wkv + (size_t)l * 1024 * 2048, nullptr, KV,
                                                2048, 2048, 1024);
    for (int b = 0; b < 2; b++) {
      scores_kernel<<<dim3(17, 16, 16), blk, 0, stream>>>(Q, KV, null_k + l * NH * DH, PR, b);
      softmax_kernel<<<16384, blk, 0, stream>>>(PR);
      mix_kernel<<<1024, blk, 0, stream>>>(PR, talk + l * 256);
      av_kernel<<<dim3(16, 16), blk, 0, stream>>>(PR, KV, null_v + l * NH * DH, O, b);
    }
    gemm_bias<<<dim3(8, 16), blk, 0, stream>>>(O, Wo + (size_t)l * 1024 * 1024, bo + l * 1024, P2,
                                               2048, 1024, 1024);
    ln_kernel<1><<<2048, blk, 0, stream>>>(P2, attn_post_g + l * 1024, attn_post_b + l * 1024, X);

    ln_kernel<0><<<2048, blk, 0, stream>>>(X, ff_pre_g + l * 1024, ff_pre_b + l * 1024, Hh);
    gemm_bias<<<dim3(43, 16), blk, 0, stream>>>(Hh, W1 + (size_t)l * 1024 * 5460, b1 + l * 5460, U,
                                                2048, 5460, 1024);
    geglu_kernel<<<dim3(11, 2048), blk, 0, stream>>>(U, GG);
    gemm_bias<<<dim3(8, 16), blk, 0, stream>>>(GG, W2 + (size_t)l * 2730 * 1024, b2 + l * 1024, P2,
                                               2048, 1024, 2730);
    ln_kernel<1><<<2048, blk, 0, stream>>>(P2, ff_post_g + l * 1024, ff_post_b + l * 1024, X);
  }
  final_kernel<<<2048, blk, 0, stream>>>(X, final_g, final_b, (float*)d_out);
}